// Round 1
// baseline (1160.821 us; speedup 1.0000x reference)
//
#include <hip/hip_runtime.h>
#include <stdint.h>

#define B_TOK 8192
#define DDIM 1024
#define HDIM 4096
#define NEXP 8
#define NROWS (B_TOK * 2)  // total routed rows (top-2)

typedef __bf16 bf16x8 __attribute__((ext_vector_type(8)));
typedef float f32x4 __attribute__((ext_vector_type(4)));

__device__ __forceinline__ unsigned short f2bf(float f) {
  unsigned int u = __float_as_uint(f);
  u += 0x7fffu + ((u >> 16) & 1u);  // round-to-nearest-even
  return (unsigned short)(u >> 16);
}

__device__ __forceinline__ void gld16(const void* g, void* l) {
  __builtin_amdgcn_global_load_lds(
      (const __attribute__((address_space(1))) void*)g,
      (__attribute__((address_space(3))) void*)l, 16, 0, 0);
}

// ---------------- gating: logits -> top2 -> renorm weights ----------------
__global__ __launch_bounds__(256) void gating_kernel(
    const float* __restrict__ x, const float* __restrict__ Wg,
    const float* __restrict__ bg, int* __restrict__ t2e,
    float* __restrict__ t2w, int* __restrict__ cnt) {
  __shared__ float sWg[NEXP * DDIM];  // [e][d] transposed for conflict-free reads
  int tid = threadIdx.x;
  for (int i = tid; i < NEXP * DDIM; i += 256) {
    int d = i >> 3, e = i & 7;
    sWg[e * DDIM + d] = Wg[i];
  }
  __syncthreads();
  int lane = tid & 63, wave = tid >> 6;
  for (int t = 0; t < 16; ++t) {
    int b = blockIdx.x * 64 + wave * 16 + t;
    float acc[NEXP];
#pragma unroll
    for (int e = 0; e < NEXP; ++e) acc[e] = 0.f;
    const float* xr = x + (size_t)b * DDIM;
#pragma unroll
    for (int j = 0; j < DDIM / 64; ++j) {
      int d = j * 64 + lane;
      float xv = xr[d];
#pragma unroll
      for (int e = 0; e < NEXP; ++e) acc[e] += xv * sWg[e * DDIM + d];
    }
#pragma unroll
    for (int off = 32; off > 0; off >>= 1) {
#pragma unroll
      for (int e = 0; e < NEXP; ++e) acc[e] += __shfl_xor(acc[e], off);
    }
    if (lane == 0) {
      float l0[NEXP];
#pragma unroll
      for (int e = 0; e < NEXP; ++e) l0[e] = acc[e] + bg[e];
      int i1 = 0;
      float v1 = l0[0];
#pragma unroll
      for (int e = 1; e < NEXP; ++e)
        if (l0[e] > v1) { v1 = l0[e]; i1 = e; }
      int i2 = (i1 == 0) ? 1 : 0;
      float v2 = l0[i2];
#pragma unroll
      for (int e = 0; e < NEXP; ++e)
        if (e != i1 && l0[e] > v2) { v2 = l0[e]; i2 = e; }
      // renormalized top-2 softmax: full denominator cancels
      float w1 = 1.f / (1.f + expf(v2 - v1));
      float w2 = 1.f - w1;
      t2e[b * 2] = i1;
      t2e[b * 2 + 1] = i2;
      t2w[b * 2] = w1;
      t2w[b * 2 + 1] = w2;
      atomicAdd(&cnt[i1], 1);
      atomicAdd(&cnt[i2], 1);
    }
  }
}

__global__ void prefix_kernel(const int* __restrict__ cnt, int* __restrict__ offs) {
  int s = 0;
  offs[0] = 0;
  for (int e = 0; e < NEXP; ++e) {
    s += cnt[e];
    offs[e + 1] = s;
  }
}

__global__ __launch_bounds__(256) void scatter_kernel(
    const int* __restrict__ t2e, const float* __restrict__ t2w,
    const int* __restrict__ offs, int* __restrict__ cursor,
    int* __restrict__ tok, float* __restrict__ tw) {
  int b = blockIdx.x * 256 + threadIdx.x;
  if (b >= B_TOK) return;
#pragma unroll
  for (int k = 0; k < 2; ++k) {
    int e = t2e[b * 2 + k];
    int pos = offs[e] + atomicAdd(&cursor[e], 1);
    tok[pos] = b;
    tw[pos] = t2w[b * 2 + k];
  }
}

// ---------------- prep: casts / transposes ----------------
__global__ __launch_bounds__(256) void cvt_x_kernel(const float* __restrict__ x,
                                                    unsigned short* __restrict__ xb) {
  size_t i = ((size_t)blockIdx.x * 256 + threadIdx.x) * 4;
  float4 v = *(const float4*)(x + i);
  ushort4 o;
  o.x = f2bf(v.x);
  o.y = f2bf(v.y);
  o.z = f2bf(v.z);
  o.w = f2bf(v.w);
  *(ushort4*)(xb + i) = o;
}

// src: [R][C] f32 (per expert in blockIdx.z) -> dst: [C][R] bf16
__global__ __launch_bounds__(256) void transpose_cvt_kernel(
    const float* __restrict__ src, unsigned short* __restrict__ dst, int R, int C) {
  __shared__ float tile[32][33];
  size_t eo = (size_t)blockIdx.z * R * C;
  int c0 = blockIdx.x * 32, r0 = blockIdx.y * 32;
  int tx = threadIdx.x & 31, ty = threadIdx.x >> 5;
#pragma unroll
  for (int i = 0; i < 4; ++i) {
    int r = r0 + ty + i * 8;
    tile[ty + i * 8][tx] = src[eo + (size_t)r * C + c0 + tx];
  }
  __syncthreads();
#pragma unroll
  for (int i = 0; i < 4; ++i) {
    int c = c0 + ty + i * 8;
    dst[eo + (size_t)c * R + r0 + tx] = f2bf(tile[tx][ty + i * 8]);
  }
}

// ---------------- GEMM1: h = gelu(x_gathered @ W1[e] + b1[e]) ----------------
// A: xb [B][D] bf16 gathered rows; B: w1t [E][H][D] bf16 ([n][k]); out hbuf [NROWS][H] bf16
__global__ __launch_bounds__(256) void gemm1_kernel(
    const unsigned short* __restrict__ xb, const unsigned short* __restrict__ w1t,
    const float* __restrict__ b1, const int* __restrict__ offs,
    const int* __restrict__ tok, unsigned short* __restrict__ hbuf) {
  int e = blockIdx.z;
  int r0 = offs[e], rows = offs[e + 1] - r0;
  int m0 = blockIdx.y * 128;
  if (m0 >= rows) return;
  int n0 = blockIdx.x * 128;

  __shared__ __attribute__((aligned(16))) unsigned short As[128 * 32];
  __shared__ __attribute__((aligned(16))) unsigned short Bs[128 * 32];

  int tid = threadIdx.x, lane = tid & 63, wave = tid >> 6;
  int u0 = wave * 2, u1 = u0 + 1;
  int sr = lane >> 2, sk = (lane & 3) * 8;
  int ar0 = u0 * 16 + sr, ar1 = u1 * 16 + sr;
  int ma0 = min(m0 + ar0, rows - 1);
  int ma1 = min(m0 + ar1, rows - 1);
  const unsigned short* pA0 = xb + (size_t)tok[r0 + ma0] * DDIM + sk;
  const unsigned short* pA1 = xb + (size_t)tok[r0 + ma1] * DDIM + sk;
  const unsigned short* pB0 = w1t + ((size_t)e * HDIM + n0 + ar0) * DDIM + sk;
  const unsigned short* pB1 = w1t + ((size_t)e * HDIM + n0 + ar1) * DDIM + sk;

  f32x4 acc[4][4];
#pragma unroll
  for (int i = 0; i < 4; ++i)
#pragma unroll
    for (int j = 0; j < 4; ++j) acc[i][j] = (f32x4){0.f, 0.f, 0.f, 0.f};

  int wm = wave & 1, wn = wave >> 1;
  int mbase = wm * 64, nbase = wn * 64;
  int fr = lane & 15, quad = lane >> 4;

  for (int kk = 0; kk < DDIM; kk += 32) {
    gld16(pA0 + kk, As + u0 * 512);
    gld16(pA1 + kk, As + u1 * 512);
    gld16(pB0 + kk, Bs + u0 * 512);
    gld16(pB1 + kk, Bs + u1 * 512);
    __syncthreads();
    bf16x8 a[4], b[4];
#pragma unroll
    for (int i = 0; i < 4; ++i) {
      a[i] = *(const bf16x8*)(As + (size_t)(mbase + i * 16 + fr) * 32 + quad * 8);
      b[i] = *(const bf16x8*)(Bs + (size_t)(nbase + i * 16 + fr) * 32 + quad * 8);
    }
#pragma unroll
    for (int i = 0; i < 4; ++i)
#pragma unroll
      for (int j = 0; j < 4; ++j)
        acc[i][j] = __builtin_amdgcn_mfma_f32_16x16x32_bf16(a[i], b[j], acc[i][j], 0, 0, 0);
    __syncthreads();
  }

  const float* b1e = b1 + (size_t)e * HDIM + n0;
#pragma unroll
  for (int i = 0; i < 4; ++i) {
    int rowb = mbase + i * 16 + quad * 4;
#pragma unroll
    for (int j = 0; j < 4; ++j) {
      int col = nbase + j * 16 + fr;
      float bias = b1e[col];
#pragma unroll
      for (int r = 0; r < 4; ++r) {
        int grow = m0 + rowb + r;
        if (grow < rows) {
          float v = acc[i][j][r] + bias;
          float g = 0.5f * v * (1.f + erff(v * 0.70710678118f));
          hbuf[(size_t)(r0 + grow) * HDIM + n0 + col] = f2bf(g);
        }
      }
    }
  }
}

// ---------------- GEMM2: out[tok] += w * (h @ W2[e] + b2[e]) ----------------
__global__ __launch_bounds__(256) void gemm2_kernel(
    const unsigned short* __restrict__ hbuf, const unsigned short* __restrict__ w2t,
    const float* __restrict__ b2, const int* __restrict__ offs,
    const int* __restrict__ tok, const float* __restrict__ tw,
    float* __restrict__ out) {
  int e = blockIdx.z;
  int r0 = offs[e], rows = offs[e + 1] - r0;
  int m0 = blockIdx.y * 128;
  if (m0 >= rows) return;
  int n0 = blockIdx.x * 128;

  __shared__ __attribute__((aligned(16))) unsigned short As[128 * 32];
  __shared__ __attribute__((aligned(16))) unsigned short Bs[128 * 32];

  int tid = threadIdx.x, lane = tid & 63, wave = tid >> 6;
  int u0 = wave * 2, u1 = u0 + 1;
  int sr = lane >> 2, sk = (lane & 3) * 8;
  int ar0 = u0 * 16 + sr, ar1 = u1 * 16 + sr;
  const unsigned short* pA0 = hbuf + (size_t)(r0 + min(m0 + ar0, rows - 1)) * HDIM + sk;
  const unsigned short* pA1 = hbuf + (size_t)(r0 + min(m0 + ar1, rows - 1)) * HDIM + sk;
  const unsigned short* pB0 = w2t + ((size_t)e * DDIM + n0 + ar0) * HDIM + sk;
  const unsigned short* pB1 = w2t + ((size_t)e * DDIM + n0 + ar1) * HDIM + sk;

  f32x4 acc[4][4];
#pragma unroll
  for (int i = 0; i < 4; ++i)
#pragma unroll
    for (int j = 0; j < 4; ++j) acc[i][j] = (f32x4){0.f, 0.f, 0.f, 0.f};

  int wm = wave & 1, wn = wave >> 1;
  int mbase = wm * 64, nbase = wn * 64;
  int fr = lane & 15, quad = lane >> 4;

  for (int kk = 0; kk < HDIM; kk += 32) {
    gld16(pA0 + kk, As + u0 * 512);
    gld16(pA1 + kk, As + u1 * 512);
    gld16(pB0 + kk, Bs + u0 * 512);
    gld16(pB1 + kk, Bs + u1 * 512);
    __syncthreads();
    bf16x8 a[4], b[4];
#pragma unroll
    for (int i = 0; i < 4; ++i) {
      a[i] = *(const bf16x8*)(As + (size_t)(mbase + i * 16 + fr) * 32 + quad * 8);
      b[i] = *(const bf16x8*)(Bs + (size_t)(nbase + i * 16 + fr) * 32 + quad * 8);
    }
#pragma unroll
    for (int i = 0; i < 4; ++i)
#pragma unroll
      for (int j = 0; j < 4; ++j)
        acc[i][j] = __builtin_amdgcn_mfma_f32_16x16x32_bf16(a[i], b[j], acc[i][j], 0, 0, 0);
    __syncthreads();
  }

  const float* b2e = b2 + (size_t)e * DDIM + n0;
#pragma unroll
  for (int i = 0; i < 4; ++i) {
    int rowb = mbase + i * 16 + quad * 4;
#pragma unroll
    for (int r = 0; r < 4; ++r) {
      int grow = m0 + rowb + r;
      if (grow < rows) {
        int trow = r0 + grow;
        int t = tok[trow];
        float w = tw[trow];
        float* orow = out + (size_t)t * DDIM + n0;
#pragma unroll
        for (int j = 0; j < 4; ++j) {
          int col = nbase + j * 16 + fr;
          float v = acc[i][j][r] + b2e[col];
          atomicAdd(orow + col, w * v);
        }
      }
    }
  }
}

extern "C" void kernel_launch(void* const* d_in, const int* in_sizes, int n_in,
                              void* d_out, int out_size, void* d_ws, size_t ws_size,
                              hipStream_t stream) {
  const float* x = (const float*)d_in[0];
  const float* Wg = (const float*)d_in[1];
  const float* bg = (const float*)d_in[2];
  const float* W1 = (const float*)d_in[3];
  const float* b1 = (const float*)d_in[4];
  const float* W2 = (const float*)d_in[5];
  const float* b2 = (const float*)d_in[6];
  float* out = (float*)d_out;

  char* ws = (char*)d_ws;
  int* cnt = (int*)ws;             // 8 ints
  int* cursor = (int*)(ws + 64);   // 8 ints
  int* offs = (int*)(ws + 128);    // 9 ints
  int* t2e = (int*)(ws + 1024);                  // 16384 ints
  float* t2w = (float*)(ws + 1024 + 65536);      // 16384 f32
  int* tok = (int*)(ws + 1024 + 131072);         // 16384 ints
  float* tw = (float*)(ws + 1024 + 196608);      // 16384 f32
  char* big = ws + 263168;
  unsigned short* xb = (unsigned short*)big;                          // 16 MB
  unsigned short* w1t = (unsigned short*)(big + 16777216);            // 64 MB
  unsigned short* w2t = (unsigned short*)(big + 16777216 + 67108864); // 64 MB
  unsigned short* hbuf = (unsigned short*)(big + 16777216 + 2 * 67108864); // 128 MB

  (void)in_sizes; (void)n_in; (void)out_size; (void)ws_size;

  hipMemsetAsync(out, 0, (size_t)B_TOK * DDIM * sizeof(float), stream);
  hipMemsetAsync(ws, 0, 1024, stream);

  cvt_x_kernel<<<(B_TOK * DDIM) / 1024, 256, 0, stream>>>(x, xb);
  transpose_cvt_kernel<<<dim3(HDIM / 32, DDIM / 32, NEXP), 256, 0, stream>>>(W1, w1t, DDIM, HDIM);
  transpose_cvt_kernel<<<dim3(DDIM / 32, HDIM / 32, NEXP), 256, 0, stream>>>(W2, w2t, HDIM, DDIM);
  gating_kernel<<<B_TOK / 64, 256, 0, stream>>>(x, Wg, bg, t2e, t2w, cnt);
  prefix_kernel<<<1, 1, 0, stream>>>(cnt, offs);
  scatter_kernel<<<B_TOK / 256, 256, 0, stream>>>(t2e, t2w, offs, cursor, tok, tw);
  gemm1_kernel<<<dim3(HDIM / 128, B_TOK / 128, NEXP), 256, 0, stream>>>(xb, w1t, b1, offs, tok, hbuf);
  gemm2_kernel<<<dim3(DDIM / 128, B_TOK / 128, NEXP), 256, 0, stream>>>(hbuf, w2t, b2, offs, tok, tw, out);
}

// Round 2
// 1047.829 us; speedup vs baseline: 1.1078x; 1.1078x over previous
//
#include <hip/hip_runtime.h>
#include <stdint.h>

#define B_TOK 8192
#define DDIM 1024
#define HDIM 4096
#define NEXP 8

typedef __bf16 bf16x8 __attribute__((ext_vector_type(8)));
typedef float f32x4 __attribute__((ext_vector_type(4)));

__device__ __forceinline__ unsigned short f2bf(float f) {
  unsigned int u = __float_as_uint(f);
  u += 0x7fffu + ((u >> 16) & 1u);  // round-to-nearest-even
  return (unsigned short)(u >> 16);
}
__device__ __forceinline__ float bfhi(unsigned int u) {  // high bf16 of packed u32
  return __uint_as_float(u & 0xffff0000u);
}
__device__ __forceinline__ float bflo(unsigned int u) {  // low bf16
  return __uint_as_float(u << 16);
}

__device__ __forceinline__ void gld16(const void* g, void* l) {
  __builtin_amdgcn_global_load_lds(
      (const __attribute__((address_space(1))) void*)g,
      (__attribute__((address_space(3))) void*)l, 16, 0, 0);
}

// tanh-form GELU; max abs err ~3e-4 (well under bf16 rounding of h)
__device__ __forceinline__ float gelu_f(float v) {
  float u = v * (0.7978845608f + 0.0356774081f * v * v);
  float ex = __expf(2.f * u);
  float th = 1.f - 2.f * __builtin_amdgcn_rcpf(ex + 1.f);  // tanh(u), saturates correctly
  return 0.5f * v * (1.f + th);
}

// ---------------- gating: logits -> top2 -> renorm weights ----------------
__global__ __launch_bounds__(256) void gating_kernel(
    const float* __restrict__ x, const float* __restrict__ Wg,
    const float* __restrict__ bg, int* __restrict__ t2e,
    float* __restrict__ t2w, int* __restrict__ cnt) {
  __shared__ float sWg[NEXP * DDIM];  // [e][d]
  int tid = threadIdx.x;
  for (int i = tid; i < NEXP * DDIM; i += 256) {
    int d = i >> 3, e = i & 7;
    sWg[e * DDIM + d] = Wg[i];
  }
  __syncthreads();
  int lane = tid & 63, wave = tid >> 6;
  for (int t = 0; t < 16; ++t) {
    int b = blockIdx.x * 64 + wave * 16 + t;
    float acc[NEXP];
#pragma unroll
    for (int e = 0; e < NEXP; ++e) acc[e] = 0.f;
    const float* xr = x + (size_t)b * DDIM;
#pragma unroll
    for (int j = 0; j < 4; ++j) {
      int d0 = j * 256 + lane * 4;
      float4 xv = *(const float4*)(xr + d0);
#pragma unroll
      for (int e = 0; e < NEXP; ++e) {
        float4 wv = *(const float4*)(sWg + e * DDIM + d0);
        acc[e] += xv.x * wv.x + xv.y * wv.y + xv.z * wv.z + xv.w * wv.w;
      }
    }
#pragma unroll
    for (int off = 32; off > 0; off >>= 1) {
#pragma unroll
      for (int e = 0; e < NEXP; ++e) acc[e] += __shfl_xor(acc[e], off);
    }
    if (lane == 0) {
      float l0[NEXP];
#pragma unroll
      for (int e = 0; e < NEXP; ++e) l0[e] = acc[e] + bg[e];
      int i1 = 0;
      float v1 = l0[0];
#pragma unroll
      for (int e = 1; e < NEXP; ++e)
        if (l0[e] > v1) { v1 = l0[e]; i1 = e; }
      int i2 = (i1 == 0) ? 1 : 0;
      float v2 = l0[i2];
#pragma unroll
      for (int e = 0; e < NEXP; ++e)
        if (e != i1 && l0[e] > v2) { v2 = l0[e]; i2 = e; }
      float w1 = 1.f / (1.f + expf(v2 - v1));  // renorm top-2 softmax
      float w2 = 1.f - w1;
      t2e[b * 2] = i1;
      t2e[b * 2 + 1] = i2;
      t2w[b * 2] = w1;
      t2w[b * 2 + 1] = w2;
      atomicAdd(&cnt[i1], 1);
      atomicAdd(&cnt[i2], 1);
    }
  }
}

// serial: offsets + flat (expert, m-tile) work queue
__global__ void prefix_kernel(const int* __restrict__ cnt, int* __restrict__ offs,
                              int* __restrict__ tileE, int* __restrict__ tileM,
                              int* __restrict__ ntile) {
  int s = 0, t = 0;
  offs[0] = 0;
  for (int e = 0; e < NEXP; ++e) {
    int c = cnt[e];
    for (int m = 0; m < c; m += 128) { tileE[t] = e; tileM[t] = m; ++t; }
    s += c;
    offs[e + 1] = s;
  }
  *ntile = t;
}

__global__ __launch_bounds__(256) void scatter_kernel(
    const int* __restrict__ t2e, const int* __restrict__ offs,
    int* __restrict__ cursor, int* __restrict__ tok, int* __restrict__ rowpos) {
  int b = blockIdx.x * 256 + threadIdx.x;
  if (b >= B_TOK) return;
#pragma unroll
  for (int k = 0; k < 2; ++k) {
    int e = t2e[b * 2 + k];
    int pos = offs[e] + atomicAdd(&cursor[e], 1);
    tok[pos] = b;
    rowpos[b * 2 + k] = pos;
  }
}

// ---------------- prep: casts / transposes ----------------
__global__ __launch_bounds__(256) void cvt_x_kernel(const float* __restrict__ x,
                                                    unsigned short* __restrict__ xb) {
  size_t i = ((size_t)blockIdx.x * 256 + threadIdx.x) * 4;
  float4 v = *(const float4*)(x + i);
  ushort4 o;
  o.x = f2bf(v.x);
  o.y = f2bf(v.y);
  o.z = f2bf(v.z);
  o.w = f2bf(v.w);
  *(ushort4*)(xb + i) = o;
}

// src [R][C] f32 (expert z) -> dst [C][R] bf16; 64x64 tiles, vectorized both sides
__global__ __launch_bounds__(256) void transpose_cvt_kernel(
    const float* __restrict__ src, unsigned short* __restrict__ dst, int R, int C) {
  __shared__ unsigned short T[64][72];
  size_t eo = (size_t)blockIdx.z * (size_t)R * C;
  int c0 = blockIdx.x * 64, r0 = blockIdx.y * 64;
  int tid = threadIdx.x;
#pragma unroll
  for (int p = 0; p < 4; ++p) {
    int idx = p * 256 + tid;
    int r = idx >> 4, c4 = (idx & 15) * 4;
    float4 v = *(const float4*)(src + eo + (size_t)(r0 + r) * C + c0 + c4);
    T[r][c4] = f2bf(v.x);
    T[r][c4 + 1] = f2bf(v.y);
    T[r][c4 + 2] = f2bf(v.z);
    T[r][c4 + 3] = f2bf(v.w);
  }
  __syncthreads();
#pragma unroll
  for (int p = 0; p < 2; ++p) {
    int idx = p * 256 + tid;
    int c = idx >> 3, s8 = (idx & 7) * 8;
    ushort4 a, b;
    a.x = T[s8][c];     a.y = T[s8 + 1][c]; a.z = T[s8 + 2][c]; a.w = T[s8 + 3][c];
    b.x = T[s8 + 4][c]; b.y = T[s8 + 5][c]; b.z = T[s8 + 6][c]; b.w = T[s8 + 7][c];
    unsigned short* dp = dst + eo + (size_t)(c0 + c) * R + r0 + s8;
    *(ushort4*)dp = a;
    *(ushort4*)(dp + 4) = b;
  }
}

// ---------------- GEMM1: h = gelu(x_gathered @ W1[e] + b1[e]) ----------------
// OPERANDS SWAPPED: a-frags = W1t rows (N dir), b-frags = token rows (M dir).
// D-fragment: row-dim (quad*4+reg) follows a (=> N, contiguous cols in hbuf row),
// col-dim (lane&15) follows b (=> token row). Verified convention from R1 pass.
__global__ __launch_bounds__(256) void gemm1_kernel(
    const unsigned short* __restrict__ xb, const unsigned short* __restrict__ w1t,
    const float* __restrict__ b1, const int* __restrict__ offs,
    const int* __restrict__ tileE, const int* __restrict__ tileM,
    const int* __restrict__ ntile, const int* __restrict__ tok,
    unsigned short* __restrict__ hbuf) {
  int ty = blockIdx.y;
  if (ty >= *ntile) return;
  int e = tileE[ty], m0 = tileM[ty];
  int r0 = offs[e], rows = offs[e + 1] - r0;
  int n0 = blockIdx.x * 128;

  __shared__ __attribute__((aligned(16))) unsigned short Ws[128 * 32];
  __shared__ __attribute__((aligned(16))) unsigned short Xs[128 * 32];

  int tid = threadIdx.x, lane = tid & 63, wave = tid >> 6;
  int u0 = wave * 2, u1 = u0 + 1;
  int sr = lane >> 2, sk = (lane & 3) * 8;
  int nr0 = u0 * 16 + sr, nr1 = u1 * 16 + sr;
  const unsigned short* pW0 = w1t + ((size_t)e * HDIM + n0 + nr0) * DDIM + sk;
  const unsigned short* pW1 = w1t + ((size_t)e * HDIM + n0 + nr1) * DDIM + sk;
  int ma0 = min(m0 + nr0, rows - 1), ma1 = min(m0 + nr1, rows - 1);
  const unsigned short* pX0 = xb + (size_t)tok[r0 + ma0] * DDIM + sk;
  const unsigned short* pX1 = xb + (size_t)tok[r0 + ma1] * DDIM + sk;

  f32x4 acc[4][4];
#pragma unroll
  for (int i = 0; i < 4; ++i)
#pragma unroll
    for (int j = 0; j < 4; ++j) acc[i][j] = (f32x4){0.f, 0.f, 0.f, 0.f};

  int wn = wave & 1, wm = wave >> 1;
  int nbase = wn * 64, mbase = wm * 64;
  int fr = lane & 15, quad = lane >> 4;

  for (int kk = 0; kk < DDIM; kk += 32) {
    gld16(pW0 + kk, Ws + u0 * 512);
    gld16(pW1 + kk, Ws + u1 * 512);
    gld16(pX0 + kk, Xs + u0 * 512);
    gld16(pX1 + kk, Xs + u1 * 512);
    __syncthreads();
    bf16x8 a[4], b[4];
#pragma unroll
    for (int i = 0; i < 4; ++i) {
      a[i] = *(const bf16x8*)(Ws + (size_t)(nbase + i * 16 + fr) * 32 + quad * 8);
      b[i] = *(const bf16x8*)(Xs + (size_t)(mbase + i * 16 + fr) * 32 + quad * 8);
    }
#pragma unroll
    for (int i = 0; i < 4; ++i)
#pragma unroll
      for (int j = 0; j < 4; ++j)
        acc[i][j] = __builtin_amdgcn_mfma_f32_16x16x32_bf16(a[i], b[j], acc[i][j], 0, 0, 0);
    __syncthreads();
  }

  const float* b1e = b1 + (size_t)e * HDIM + n0 + nbase;
  float4 bias[4];
#pragma unroll
  for (int i = 0; i < 4; ++i) bias[i] = *(const float4*)(b1e + i * 16 + quad * 4);
#pragma unroll
  for (int j = 0; j < 4; ++j) {
    int grow = m0 + mbase + j * 16 + fr;
    if (grow < rows) {
      unsigned short* hp = hbuf + (size_t)(r0 + grow) * HDIM + n0 + nbase;
#pragma unroll
      for (int i = 0; i < 4; ++i) {
        ushort4 o;
        o.x = f2bf(gelu_f(acc[i][j][0] + bias[i].x));
        o.y = f2bf(gelu_f(acc[i][j][1] + bias[i].y));
        o.z = f2bf(gelu_f(acc[i][j][2] + bias[i].z));
        o.w = f2bf(gelu_f(acc[i][j][3] + bias[i].w));
        *(ushort4*)(hp + i * 16 + quad * 4) = o;
      }
    }
  }
}

// ---------------- GEMM2: ybuf[row] = h[row] @ W2[e] + b2[e] (no atomics) ----------------
__global__ __launch_bounds__(256) void gemm2_kernel(
    const unsigned short* __restrict__ hbuf, const unsigned short* __restrict__ w2t,
    const float* __restrict__ b2, const int* __restrict__ offs,
    const int* __restrict__ tileE, const int* __restrict__ tileM,
    const int* __restrict__ ntile, unsigned short* __restrict__ ybuf) {
  int ty = blockIdx.y;
  if (ty >= *ntile) return;
  int e = tileE[ty], m0 = tileM[ty];
  int r0 = offs[e], rows = offs[e + 1] - r0;
  int n0 = blockIdx.x * 128;

  __shared__ __attribute__((aligned(16))) unsigned short Ws[128 * 32];
  __shared__ __attribute__((aligned(16))) unsigned short Hs[128 * 32];

  int tid = threadIdx.x, lane = tid & 63, wave = tid >> 6;
  int u0 = wave * 2, u1 = u0 + 1;
  int sr = lane >> 2, sk = (lane & 3) * 8;
  int nr0 = u0 * 16 + sr, nr1 = u1 * 16 + sr;
  const unsigned short* pW0 = w2t + ((size_t)e * DDIM + n0 + nr0) * HDIM + sk;
  const unsigned short* pW1 = w2t + ((size_t)e * DDIM + n0 + nr1) * HDIM + sk;
  const unsigned short* pH0 = hbuf + (size_t)(r0 + min(m0 + nr0, rows - 1)) * HDIM + sk;
  const unsigned short* pH1 = hbuf + (size_t)(r0 + min(m0 + nr1, rows - 1)) * HDIM + sk;

  f32x4 acc[4][4];
#pragma unroll
  for (int i = 0; i < 4; ++i)
#pragma unroll
    for (int j = 0; j < 4; ++j) acc[i][j] = (f32x4){0.f, 0.f, 0.f, 0.f};

  int wn = wave & 1, wm = wave >> 1;
  int nbase = wn * 64, mbase = wm * 64;
  int fr = lane & 15, quad = lane >> 4;

  for (int kk = 0; kk < HDIM; kk += 32) {
    gld16(pW0 + kk, Ws + u0 * 512);
    gld16(pW1 + kk, Ws + u1 * 512);
    gld16(pH0 + kk, Hs + u0 * 512);
    gld16(pH1 + kk, Hs + u1 * 512);
    __syncthreads();
    bf16x8 a[4], b[4];
#pragma unroll
    for (int i = 0; i < 4; ++i) {
      a[i] = *(const bf16x8*)(Ws + (size_t)(nbase + i * 16 + fr) * 32 + quad * 8);
      b[i] = *(const bf16x8*)(Hs + (size_t)(mbase + i * 16 + fr) * 32 + quad * 8);
    }
#pragma unroll
    for (int i = 0; i < 4; ++i)
#pragma unroll
      for (int j = 0; j < 4; ++j)
        acc[i][j] = __builtin_amdgcn_mfma_f32_16x16x32_bf16(a[i], b[j], acc[i][j], 0, 0, 0);
    __syncthreads();
  }

  const float* b2e = b2 + (size_t)e * DDIM + n0 + nbase;
  float4 bias[4];
#pragma unroll
  for (int i = 0; i < 4; ++i) bias[i] = *(const float4*)(b2e + i * 16 + quad * 4);
#pragma unroll
  for (int j = 0; j < 4; ++j) {
    int grow = m0 + mbase + j * 16 + fr;
    if (grow < rows) {
      unsigned short* yp = ybuf + (size_t)(r0 + grow) * DDIM + n0 + nbase;
#pragma unroll
      for (int i = 0; i < 4; ++i) {
        ushort4 o;
        o.x = f2bf(acc[i][j][0] + bias[i].x);
        o.y = f2bf(acc[i][j][1] + bias[i].y);
        o.z = f2bf(acc[i][j][2] + bias[i].z);
        o.w = f2bf(acc[i][j][3] + bias[i].w);
        *(ushort4*)(yp + i * 16 + quad * 4) = o;
      }
    }
  }
}

// ---------------- combine: out[b] = w0*y[row0] + w1*y[row1] ----------------
__global__ __launch_bounds__(256) void combine_kernel(
    const unsigned short* __restrict__ ybuf, const int* __restrict__ rowpos,
    const float* __restrict__ t2w, float* __restrict__ out) {
  int idx = blockIdx.x * 256 + threadIdx.x;  // B*D/8 threads
  int b = idx >> 7;
  int c8 = (idx & 127) * 8;
  int p0 = rowpos[b * 2], p1 = rowpos[b * 2 + 1];
  float w0 = t2w[b * 2], w1 = t2w[b * 2 + 1];
  uint4 ya = *(const uint4*)(ybuf + (size_t)p0 * DDIM + c8);
  uint4 yb = *(const uint4*)(ybuf + (size_t)p1 * DDIM + c8);
  float4 o0, o1;
  o0.x = w0 * bflo(ya.x) + w1 * bflo(yb.x);
  o0.y = w0 * bfhi(ya.x) + w1 * bfhi(yb.x);
  o0.z = w0 * bflo(ya.y) + w1 * bflo(yb.y);
  o0.w = w0 * bfhi(ya.y) + w1 * bfhi(yb.y);
  o1.x = w0 * bflo(ya.z) + w1 * bflo(yb.z);
  o1.y = w0 * bfhi(ya.z) + w1 * bfhi(yb.z);
  o1.z = w0 * bflo(ya.w) + w1 * bflo(yb.w);
  o1.w = w0 * bfhi(ya.w) + w1 * bfhi(yb.w);
  float* op = out + (size_t)b * DDIM + c8;
  *(float4*)op = o0;
  *(float4*)(op + 4) = o1;
}

extern "C" void kernel_launch(void* const* d_in, const int* in_sizes, int n_in,
                              void* d_out, int out_size, void* d_ws, size_t ws_size,
                              hipStream_t stream) {
  const float* x = (const float*)d_in[0];
  const float* Wg = (const float*)d_in[1];
  const float* bg = (const float*)d_in[2];
  const float* W1 = (const float*)d_in[3];
  const float* b1 = (const float*)d_in[4];
  const float* W2 = (const float*)d_in[5];
  const float* b2 = (const float*)d_in[6];
  float* out = (float*)d_out;

  char* ws = (char*)d_ws;
  int* cnt = (int*)(ws + 0);
  int* cursor = (int*)(ws + 64);
  int* offs = (int*)(ws + 128);
  int* ntile = (int*)(ws + 192);
  int* tileE = (int*)(ws + 256);
  int* tileM = (int*)(ws + 896);
  int* t2e = (int*)(ws + 2048);
  float* t2w = (float*)(ws + 67584);
  int* tok = (int*)(ws + 133120);
  int* rowpos = (int*)(ws + 198656);
  char* big = ws + 264192;
  unsigned short* xb = (unsigned short*)big;                              // 16 MiB
  unsigned short* w1t = (unsigned short*)(big + 16777216);                // 64 MiB
  unsigned short* ybuf = w1t;  // alias: w1t dead after gemm1; ybuf needs 32 MiB
  unsigned short* w2t = (unsigned short*)(big + 16777216 + 67108864);     // 64 MiB
  unsigned short* hbuf = (unsigned short*)(big + 16777216 + 2 * 67108864);// 128 MiB

  (void)in_sizes; (void)n_in; (void)out_size; (void)ws_size;

  hipMemsetAsync(ws, 0, 256, stream);

  cvt_x_kernel<<<(B_TOK * DDIM) / 1024, 256, 0, stream>>>(x, xb);
  transpose_cvt_kernel<<<dim3(HDIM / 64, DDIM / 64, NEXP), 256, 0, stream>>>(W1, w1t, DDIM, HDIM);
  transpose_cvt_kernel<<<dim3(DDIM / 64, HDIM / 64, NEXP), 256, 0, stream>>>(W2, w2t, HDIM, DDIM);
  gating_kernel<<<B_TOK / 64, 256, 0, stream>>>(x, Wg, bg, t2e, t2w, cnt);
  prefix_kernel<<<1, 1, 0, stream>>>(cnt, offs, tileE, tileM, ntile);
  scatter_kernel<<<B_TOK / 256, 256, 0, stream>>>(t2e, offs, cursor, tok, rowpos);
  gemm1_kernel<<<dim3(HDIM / 128, 136), 256, 0, stream>>>(xb, w1t, b1, offs, tileE, tileM, ntile, tok, hbuf);
  gemm2_kernel<<<dim3(DDIM / 128, 136), 256, 0, stream>>>(hbuf, w2t, b2, offs, tileE, tileM, ntile, ybuf);
  combine_kernel<<<(B_TOK * DDIM) / (256 * 8), 256, 0, stream>>>(ybuf, rowpos, t2w, out);
}